// Round 6
// baseline (80.079 us; speedup 1.0000x reference)
//
#include <hip/hip_runtime.h>

// Pfaffian of 128 gathered 128x128 skew-symmetric f32 matrices, Parlett-Reid
// LTL^T. One 512-thread block per matrix. Base: r22 (4-wide panels, wave->row
// permutation, wave-0 specialization, POFF padding, LDS-broadcast crew
// pre-update, bulk window load batching).
//
// r23 (this round): CHAIN SHUFFLE BATCHING. The crew chain's cross-lane
// scalar fetches (tau_r/col_r/tau_c/col_c per j2) switch from serialized
// v_readlane (VALU->SGPR->VALU hazard each) to batched __shfl
// (ds_bpermute): all 4*(3-j) fetches of a step issue as independent LDS
// permutes whose latencies overlap, then the FMAs run. Same values,
// bit-identical trajectory. Pivot stays readlane (SGPR operand feeds the
// div for free).
//
// EVIDENCE LEDGER: r19 (+3072 crew fma -> +1.7us) => crew issue ~1.3cyc/fma
// real. NEUTRAL (exonerated): crew pre-update cost (r15/r16/r18), SIMD
// contention + prologue (r21), bulk LDS latency (r22). Remaining
// unfalsified pole: crew chain readlane hazard serialization (this round).
//
// NUMERICS LEDGER: np ref is the XLA-CPU f32 trajectory:
//     tmp = fma(tau_r, col_c, A);  A' = fma(-col_r, tau_c, tmp)
// tau = __fdiv_rn(row_k, piv), pf = __fmul_rn in step order. Dead indices
// staged/published as exact 0.0f -> identity FMAs on never-read entries.
// Expected absmax fingerprint: 0.0234375 exactly (else restructure bug).
//
// PERF LEDGER (bench): r13 76.1 (BEST) -> r14 79.7 regr -> r15 77.3 ->
// r16 76.2 -> r18 76.55 -> r19 78.27 regr -> r21 77.10 -> r22 77.91.
// Noise band since r13: 76.1-77.9. r23 predict 74-76 if hazard theory
// right; neutral => serial spine is at its structural floor.

#define POFF(i) ((i) + (((i) >> 5) << 2))   // 4-float pad every 32 floats
#define RL(v, l) __int_as_float(__builtin_amdgcn_readlane(__float_as_int(v), (l)))

__global__ __launch_bounds__(512) void pfaffian_kernel(
    const float* __restrict__ x,    // [128, 128]
    const float* __restrict__ F,    // [32640] packed strict lower tri of 256x256
    float* __restrict__ out)        // [128]
{
    const int b    = blockIdx.x;
    const int t    = threadIdx.x;
    const int lane = t & 63;
    const int wave = t >> 6;        // 0..7

    __shared__ int idx_sh[128];
    __shared__ int wtot[4];
    __shared__ __align__(16) float tauLDS[2][4][144];
    __shared__ __align__(16) float colLDS[2][4][144];
    __shared__ __align__(16) float rS[2][4][144];   // panel row vecs k0,k0+2,k0+4,k0+6
    __shared__ __align__(16) float cS[2][4][144];   // panel col vecs k0+1,+3,+5,+7

    // ---- occupancy -> sorted index list (certified r0-r22) ----
    if (t < 256) {
        const float xv  = x[b * 128 + (t & 127)];
        const bool  pos = xv > 0.0f;
        const bool  o   = (t < 128) ? pos : !pos;
        const unsigned long long mm = __ballot(o);
        const int rank = __popcll(mm & ((1ull << lane) - 1ull));
        if (lane == 63) wtot[wave] = rank + (o ? 1 : 0);
        __syncthreads();
        int off = 0;
#pragma unroll
        for (int w = 0; w < 4; ++w)
            if (w < wave) off += wtot[w];
        if (o) idx_sh[off + rank] = t;
    } else {
        __syncthreads();   // matches the barrier inside the t<256 branch
    }
    __syncthreads();

    // ---- wave -> panel-pair ownership permutation (r21a) ----
    const int m = (wave == 0) ? 0 : (wave <= 3 ? 8 - wave : wave - 3);

    // ---- 4x8 block ownership (rows permuted by m) ----
    const int rg   = (m << 2) | ((t >> 4) & 3);   // row-group 0..31
    const int cg   = t & 15;                      // cols [cg*8, cg*8+8)
    const int row0 = rg << 2;
    const int col0 = cg << 3;
    const int prow = POFF(row0);
    const int pcol = POFF(col0);

    // raw A element (pre-elimination), same formula as the register gather
    auto Fval = [&](int gi, int gj) -> float {
        const int ii = idx_sh[gi];
        const int jj = idx_sh[gj];
        if (ii == jj) return 0.0f;                 // only hit when gi == gj
        const int hi = ii > jj ? ii : jj;
        const int lo = ii > jj ? jj : ii;
        const float v = F[(hi * (hi - 1)) / 2 + lo];
        return (ii < jj) ? -v : v;
    };

    float A[4][8];
    if (wave >= 1) {
        int ri[4], ci[8];
#pragma unroll
        for (int a = 0; a < 4; ++a) ri[a] = idx_sh[row0 + a];
#pragma unroll
        for (int c = 0; c < 8; ++c) ci[c] = idx_sh[col0 + c];
#pragma unroll
        for (int a = 0; a < 4; ++a) {
            const int ii = ri[a];
#pragma unroll
            for (int c = 0; c < 8; ++c) {
                const int jj = ci[c];
                const int hi = ii > jj ? ii : jj;
                const int lo = ii > jj ? jj : ii;
                float v = (ii == jj) ? 0.0f : F[(hi * (hi - 1)) / 2 + lo];
                A[a][c] = (ii < jj) ? -v : v;
            }
        }
    }

    // stage panel Pn (rgbase = 2*Pn, cgbase = Pn) into set st (bulk only)
    auto stage = [&](int Pn, int st) {
        const int rgbase = 2 * Pn;
        if (rg == rgbase) {
            *(float4*)&rS[st][0][pcol]     = make_float4(A[0][0], A[0][1], A[0][2], A[0][3]);
            *(float4*)&rS[st][0][pcol + 4] = make_float4(A[0][4], A[0][5], A[0][6], A[0][7]);
            *(float4*)&rS[st][1][pcol]     = make_float4(A[2][0], A[2][1], A[2][2], A[2][3]);
            *(float4*)&rS[st][1][pcol + 4] = make_float4(A[2][4], A[2][5], A[2][6], A[2][7]);
        }
        if (rg == rgbase + 1) {
            *(float4*)&rS[st][2][pcol]     = make_float4(A[0][0], A[0][1], A[0][2], A[0][3]);
            *(float4*)&rS[st][2][pcol + 4] = make_float4(A[0][4], A[0][5], A[0][6], A[0][7]);
            *(float4*)&rS[st][3][pcol]     = make_float4(A[2][0], A[2][1], A[2][2], A[2][3]);
            *(float4*)&rS[st][3][pcol + 4] = make_float4(A[2][4], A[2][5], A[2][6], A[2][7]);
        }
        if (cg == Pn) {
            *(float4*)&cS[st][0][prow] = make_float4(A[0][1], A[1][1], A[2][1], A[3][1]);
            *(float4*)&cS[st][1][prow] = make_float4(A[0][3], A[1][3], A[2][3], A[3][3]);
            *(float4*)&cS[st][2][prow] = make_float4(A[0][5], A[1][5], A[2][5], A[3][5]);
            *(float4*)&cS[st][3][prow] = make_float4(A[0][7], A[1][7], A[2][7], A[3][7]);
        }
    };

    float pf = 1.0f;

    // crew for panel Pn: pre-update with panel Pn-1 (if pre), chain, publish.
    auto crew2 = [&](int Pn, bool pre) {
        const int sv = Pn & 1;
        const int g0 = lane << 1;
        const int g1 = g0 + 1;
        const int pg = POFF(g0);
        float R[4][2], C[4][2];
#pragma unroll
        for (int j = 0; j < 4; ++j) {
            const float2 rv = *(const float2*)&rS[sv][j][pg];
            const float2 cv = *(const float2*)&cS[sv][j][pg];
            R[j][0] = rv.x; R[j][1] = rv.y;
            C[j][0] = cv.x; C[j][1] = cv.y;
        }
        if (pre) {
            const int svp  = sv ^ 1;
            const int base = POFF(8 * Pn);   // contiguous, inside one pad block
            float4 Tq[4][2], Cq[4][2];
#pragma unroll
            for (int jp = 0; jp < 4; ++jp) {   // batched broadcast loads
                Tq[jp][0] = *(const float4*)&tauLDS[svp][jp][base];
                Tq[jp][1] = *(const float4*)&tauLDS[svp][jp][base + 4];
                Cq[jp][0] = *(const float4*)&colLDS[svp][jp][base];
                Cq[jp][1] = *(const float4*)&colLDS[svp][jp][base + 4];
            }
#pragma unroll
            for (int jp = 0; jp < 4; ++jp) {
                const float trA[4] = {Tq[jp][0].x, Tq[jp][0].z, Tq[jp][1].x, Tq[jp][1].z};
                const float crA[4] = {Cq[jp][0].x, Cq[jp][0].z, Cq[jp][1].x, Cq[jp][1].z};
                const float tcA[4] = {Tq[jp][0].y, Tq[jp][0].w, Tq[jp][1].y, Tq[jp][1].w};
                const float ccA[4] = {Cq[jp][0].y, Cq[jp][0].w, Cq[jp][1].y, Cq[jp][1].w};
                const float2 tpv = *(const float2*)&tauLDS[svp][jp][pg];
                const float2 cpv = *(const float2*)&colLDS[svp][jp][pg];
#pragma unroll
                for (int a = 0; a < 4; ++a) {
                    const float tau_r = trA[a];
                    const float col_r = crA[a];
                    R[a][0] = __fmaf_rn(-col_r, tpv.x,
                              __fmaf_rn(tau_r, cpv.x, R[a][0]));
                    R[a][1] = __fmaf_rn(-col_r, tpv.y,
                              __fmaf_rn(tau_r, cpv.y, R[a][1]));
                    const float tau_c = tcA[a];
                    const float col_c = ccA[a];
                    C[a][0] = __fmaf_rn(-cpv.x, tau_c,
                              __fmaf_rn(tpv.x, col_c, C[a][0]));
                    C[a][1] = __fmaf_rn(-cpv.y, tau_c,
                              __fmaf_rn(tpv.y, col_c, C[a][1]));
                }
            }
        }
        // ---- chain: r23 batched-shuffle form (same values, same fma order)
        float TAU[4][2], CV[4][2];
#pragma unroll
        for (int j = 0; j < 4; ++j) {
            const int k = 8 * Pn + 2 * j;
            const float piv = RL(R[j][1], 4 * Pn + j);
            pf = __fmul_rn(pf, piv);          // step order
            TAU[j][0] = (g0 > k + 1) ? __fdiv_rn(R[j][0], piv) : 0.0f;
            TAU[j][1] = (g1 > k + 1) ? __fdiv_rn(R[j][1], piv) : 0.0f;
            CV[j][0]  = (g0 > k + 1) ? C[j][0] : 0.0f;
            CV[j][1]  = (g1 > k + 1) ? C[j][1] : 0.0f;
            *(float2*)&tauLDS[sv][j][pg] = make_float2(TAU[j][0], TAU[j][1]);
            *(float2*)&colLDS[sv][j][pg] = make_float2(CV[j][0], CV[j][1]);
            // batched cross-lane fetches: independent ds_bpermute, latencies
            // overlap under one drain (vs serialized readlane hazards)
            float trs[3], crs[3], tcs[3], ccs[3];
#pragma unroll
            for (int j2 = j + 1; j2 < 4; ++j2) {
                const int q  = j2 - j - 1;
                const int ls = 4 * Pn + j2;
                trs[q] = __shfl(TAU[j][0], ls, 64);
                crs[q] = __shfl(CV[j][0],  ls, 64);
                tcs[q] = __shfl(TAU[j][1], ls, 64);
                ccs[q] = __shfl(CV[j][1],  ls, 64);
            }
#pragma unroll
            for (int j2 = j + 1; j2 < 4; ++j2) {
                const int q = j2 - j - 1;
                R[j2][0] = __fmaf_rn(-crs[q], TAU[j][0],
                           __fmaf_rn(trs[q], CV[j][0], R[j2][0]));
                R[j2][1] = __fmaf_rn(-crs[q], TAU[j][1],
                           __fmaf_rn(trs[q], CV[j][1], R[j2][1]));
                C[j2][0] = __fmaf_rn(-CV[j][0], tcs[q],
                           __fmaf_rn(TAU[j][0], ccs[q], C[j2][0]));
                C[j2][1] = __fmaf_rn(-CV[j][1], tcs[q],
                           __fmaf_rn(TAU[j][1], ccs[q], C[j2][1]));
            }
        }
    };

    // ---- wave 0: panel-0/1 heads direct from F, then crew(0), overlapped
    //      with the bulk waves' A-gather (r21b). In-wave RAW, no barrier.
    if (wave == 0) {
        const int c0 = lane << 1;
        const int pc = POFF(c0);
#pragma unroll
        for (int st = 0; st < 2; ++st) {
#pragma unroll
            for (int j = 0; j < 4; ++j) {
                const int k = 8 * st + 2 * j;
                float2 rv, cv;
                rv.x = Fval(k, c0);
                rv.y = Fval(k, c0 + 1);
                cv.x = Fval(c0, k + 1);
                cv.y = Fval(c0 + 1, k + 1);
                *(float2*)&rS[st][j][pc] = rv;
                *(float2*)&cS[st][j][pc] = cv;
            }
        }
        crew2(0, false);
    }
    __syncthreads();

    // ---- 15 windows, ONE barrier each: bulk panel P || crew panel P+1 ----
    // wave w bulk-active for P < 2m. All 24 float4 LDS loads of the window
    // batched up-front (r22).
    for (int P = 0; P < 15; ++P) {
        if (wave >= 1 && P < 2 * m) {
            const int sp = P & 1;
            float4 TRv[4], CRv[4], T0v[4], T1v[4], C0v[4], C1v[4];
#pragma unroll
            for (int j = 0; j < 4; ++j) {
                TRv[j] = *(const float4*)&tauLDS[sp][j][prow];
                CRv[j] = *(const float4*)&colLDS[sp][j][prow];
                T0v[j] = *(const float4*)&tauLDS[sp][j][pcol];
                T1v[j] = *(const float4*)&tauLDS[sp][j][pcol + 4];
                C0v[j] = *(const float4*)&colLDS[sp][j][pcol];
                C1v[j] = *(const float4*)&colLDS[sp][j][pcol + 4];
            }
#pragma unroll
            for (int j = 0; j < 4; ++j) {
                const float tr[4] = {TRv[j].x, TRv[j].y, TRv[j].z, TRv[j].w};
                const float cr[4] = {CRv[j].x, CRv[j].y, CRv[j].z, CRv[j].w};
                const float tc[8] = {T0v[j].x, T0v[j].y, T0v[j].z, T0v[j].w,
                                     T1v[j].x, T1v[j].y, T1v[j].z, T1v[j].w};
                const float cc[8] = {C0v[j].x, C0v[j].y, C0v[j].z, C0v[j].w,
                                     C1v[j].x, C1v[j].y, C1v[j].z, C1v[j].w};
#pragma unroll
                for (int a = 0; a < 4; ++a) {
#pragma unroll
                    for (int c = 0; c < 8; ++c) {
                        A[a][c] = __fmaf_rn(-cr[a], tc[c],
                                  __fmaf_rn(tr[a], cc[c], A[a][c]));
                    }
                }
            }
            if (P <= 13) stage(P + 2, P & 1);   // updated through P
        }
        if (wave == 0) crew2(P + 1, true);      // panels 1..15
        __syncthreads();
    }

    if (t == 0) out[b] = pf;
}

extern "C" void kernel_launch(void* const* d_in, const int* in_sizes, int n_in,
                              void* d_out, int out_size, void* d_ws, size_t ws_size,
                              hipStream_t stream) {
    const float* x = (const float*)d_in[0];   // [128*128]
    const float* F = (const float*)d_in[1];   // [32640]
    float* out     = (float*)d_out;           // [128]
    (void)in_sizes; (void)n_in; (void)out_size; (void)d_ws; (void)ws_size;

    pfaffian_kernel<<<128, 512, 0, stream>>>(x, F, out);
}

// Round 7
// 77.309 us; speedup vs baseline: 1.0358x; 1.0358x over previous
//
#include <hip/hip_runtime.h>

// Pfaffian of 128 gathered 128x128 skew-symmetric f32 matrices, Parlett-Reid
// LTL^T. One 512-thread block per matrix. Base: r22 structure (4-wide
// panels, wave->row permutation, wave-0 specialization, POFF padding,
// LDS-broadcast crew pre-update, bulk window load batching).
//
// r24 (this round):
//  (1) REVERT r23 shuffle chain -> readlane (r23 regressed +2.2us:
//      ds_bpermute is LDS-pipe, readlane is cheap; lesson recorded).
//  (2) RECIPROCAL PROBE: per chain step, ONE __fdiv_rn(1,piv) + two
//      __fmul_rn replaces two __fdiv_rn. Halves div sequences on the
//      serial crew spine (64 -> 32 per matrix). FIRST deliberate
//      trajectory change (tau differs <=1ulp): doubles as a TOLERANCE
//      PROBE for the planned head-racer restructure (which needs rcp-mul
//      taus to be cheap). absmax WILL change from 0.0234375 - expect
//      0.01-0.05, PASS. If FAIL: bit-identity is a hard constraint ->
//      revert and plateau.
//
// EVIDENCE LEDGER: crew chain work is the spine (r19: +fma -> +1.7us;
// r23: +ds_bpermute -> +2.2us). NEUTRAL/exonerated: crew pre-update cost
// (r15/16/18), SIMD contention + prologue (r21), bulk LDS latency (r22).
// Window loop runs at crew latency; only crew-spine cuts can win now.
//
// NUMERICS LEDGER: np ref is the XLA-CPU f32 trajectory:
//     tmp = fma(tau_r, col_c, A);  A' = fma(-col_r, tau_c, tmp)
// r24 changes tau rounding: tau = R * fdiv_rn(1,piv) (was fdiv_rn(R,piv)).
// pf = __fmul_rn in step order unchanged. Dead indices still exact 0.0f.
//
// PERF LEDGER (bench): r13 76.1 (BEST) -> r14 79.7 -> r15 77.3 -> r16 76.2
// -> r18 76.55 -> r19 78.27 -> r21 77.10 -> r22 77.91 -> r23 80.08 REGR.
// r24 predict 76.3-77.4, absmax 0.01-0.05 PASS (tolerance probe).

#define POFF(i) ((i) + (((i) >> 5) << 2))   // 4-float pad every 32 floats
#define RL(v, l) __int_as_float(__builtin_amdgcn_readlane(__float_as_int(v), (l)))

__global__ __launch_bounds__(512) void pfaffian_kernel(
    const float* __restrict__ x,    // [128, 128]
    const float* __restrict__ F,    // [32640] packed strict lower tri of 256x256
    float* __restrict__ out)        // [128]
{
    const int b    = blockIdx.x;
    const int t    = threadIdx.x;
    const int lane = t & 63;
    const int wave = t >> 6;        // 0..7

    __shared__ int idx_sh[128];
    __shared__ int wtot[4];
    __shared__ __align__(16) float tauLDS[2][4][144];
    __shared__ __align__(16) float colLDS[2][4][144];
    __shared__ __align__(16) float rS[2][4][144];   // panel row vecs k0,k0+2,k0+4,k0+6
    __shared__ __align__(16) float cS[2][4][144];   // panel col vecs k0+1,+3,+5,+7

    // ---- occupancy -> sorted index list (certified r0-r23) ----
    if (t < 256) {
        const float xv  = x[b * 128 + (t & 127)];
        const bool  pos = xv > 0.0f;
        const bool  o   = (t < 128) ? pos : !pos;
        const unsigned long long mm = __ballot(o);
        const int rank = __popcll(mm & ((1ull << lane) - 1ull));
        if (lane == 63) wtot[wave] = rank + (o ? 1 : 0);
        __syncthreads();
        int off = 0;
#pragma unroll
        for (int w = 0; w < 4; ++w)
            if (w < wave) off += wtot[w];
        if (o) idx_sh[off + rank] = t;
    } else {
        __syncthreads();   // matches the barrier inside the t<256 branch
    }
    __syncthreads();

    // ---- wave -> panel-pair ownership permutation (r21a) ----
    const int m = (wave == 0) ? 0 : (wave <= 3 ? 8 - wave : wave - 3);

    // ---- 4x8 block ownership (rows permuted by m) ----
    const int rg   = (m << 2) | ((t >> 4) & 3);   // row-group 0..31
    const int cg   = t & 15;                      // cols [cg*8, cg*8+8)
    const int row0 = rg << 2;
    const int col0 = cg << 3;
    const int prow = POFF(row0);
    const int pcol = POFF(col0);

    // raw A element (pre-elimination), same formula as the register gather
    auto Fval = [&](int gi, int gj) -> float {
        const int ii = idx_sh[gi];
        const int jj = idx_sh[gj];
        if (ii == jj) return 0.0f;                 // only hit when gi == gj
        const int hi = ii > jj ? ii : jj;
        const int lo = ii > jj ? jj : ii;
        const float v = F[(hi * (hi - 1)) / 2 + lo];
        return (ii < jj) ? -v : v;
    };

    float A[4][8];
    if (wave >= 1) {
        int ri[4], ci[8];
#pragma unroll
        for (int a = 0; a < 4; ++a) ri[a] = idx_sh[row0 + a];
#pragma unroll
        for (int c = 0; c < 8; ++c) ci[c] = idx_sh[col0 + c];
#pragma unroll
        for (int a = 0; a < 4; ++a) {
            const int ii = ri[a];
#pragma unroll
            for (int c = 0; c < 8; ++c) {
                const int jj = ci[c];
                const int hi = ii > jj ? ii : jj;
                const int lo = ii > jj ? jj : ii;
                float v = (ii == jj) ? 0.0f : F[(hi * (hi - 1)) / 2 + lo];
                A[a][c] = (ii < jj) ? -v : v;
            }
        }
    }

    // stage panel Pn (rgbase = 2*Pn, cgbase = Pn) into set st (bulk only)
    auto stage = [&](int Pn, int st) {
        const int rgbase = 2 * Pn;
        if (rg == rgbase) {
            *(float4*)&rS[st][0][pcol]     = make_float4(A[0][0], A[0][1], A[0][2], A[0][3]);
            *(float4*)&rS[st][0][pcol + 4] = make_float4(A[0][4], A[0][5], A[0][6], A[0][7]);
            *(float4*)&rS[st][1][pcol]     = make_float4(A[2][0], A[2][1], A[2][2], A[2][3]);
            *(float4*)&rS[st][1][pcol + 4] = make_float4(A[2][4], A[2][5], A[2][6], A[2][7]);
        }
        if (rg == rgbase + 1) {
            *(float4*)&rS[st][2][pcol]     = make_float4(A[0][0], A[0][1], A[0][2], A[0][3]);
            *(float4*)&rS[st][2][pcol + 4] = make_float4(A[0][4], A[0][5], A[0][6], A[0][7]);
            *(float4*)&rS[st][3][pcol]     = make_float4(A[2][0], A[2][1], A[2][2], A[2][3]);
            *(float4*)&rS[st][3][pcol + 4] = make_float4(A[2][4], A[2][5], A[2][6], A[2][7]);
        }
        if (cg == Pn) {
            *(float4*)&cS[st][0][prow] = make_float4(A[0][1], A[1][1], A[2][1], A[3][1]);
            *(float4*)&cS[st][1][prow] = make_float4(A[0][3], A[1][3], A[2][3], A[3][3]);
            *(float4*)&cS[st][2][prow] = make_float4(A[0][5], A[1][5], A[2][5], A[3][5]);
            *(float4*)&cS[st][3][prow] = make_float4(A[0][7], A[1][7], A[2][7], A[3][7]);
        }
    };

    float pf = 1.0f;

    // crew for panel Pn: pre-update with panel Pn-1 (if pre), chain, publish.
    auto crew2 = [&](int Pn, bool pre) {
        const int sv = Pn & 1;
        const int g0 = lane << 1;
        const int g1 = g0 + 1;
        const int pg = POFF(g0);
        float R[4][2], C[4][2];
#pragma unroll
        for (int j = 0; j < 4; ++j) {
            const float2 rv = *(const float2*)&rS[sv][j][pg];
            const float2 cv = *(const float2*)&cS[sv][j][pg];
            R[j][0] = rv.x; R[j][1] = rv.y;
            C[j][0] = cv.x; C[j][1] = cv.y;
        }
        if (pre) {
            const int svp  = sv ^ 1;
            const int base = POFF(8 * Pn);   // contiguous, inside one pad block
            float4 Tq[4][2], Cq[4][2];
#pragma unroll
            for (int jp = 0; jp < 4; ++jp) {   // batched broadcast loads
                Tq[jp][0] = *(const float4*)&tauLDS[svp][jp][base];
                Tq[jp][1] = *(const float4*)&tauLDS[svp][jp][base + 4];
                Cq[jp][0] = *(const float4*)&colLDS[svp][jp][base];
                Cq[jp][1] = *(const float4*)&colLDS[svp][jp][base + 4];
            }
#pragma unroll
            for (int jp = 0; jp < 4; ++jp) {
                const float trA[4] = {Tq[jp][0].x, Tq[jp][0].z, Tq[jp][1].x, Tq[jp][1].z};
                const float crA[4] = {Cq[jp][0].x, Cq[jp][0].z, Cq[jp][1].x, Cq[jp][1].z};
                const float tcA[4] = {Tq[jp][0].y, Tq[jp][0].w, Tq[jp][1].y, Tq[jp][1].w};
                const float ccA[4] = {Cq[jp][0].y, Cq[jp][0].w, Cq[jp][1].y, Cq[jp][1].w};
                const float2 tpv = *(const float2*)&tauLDS[svp][jp][pg];
                const float2 cpv = *(const float2*)&colLDS[svp][jp][pg];
#pragma unroll
                for (int a = 0; a < 4; ++a) {
                    const float tau_r = trA[a];
                    const float col_r = crA[a];
                    R[a][0] = __fmaf_rn(-col_r, tpv.x,
                              __fmaf_rn(tau_r, cpv.x, R[a][0]));
                    R[a][1] = __fmaf_rn(-col_r, tpv.y,
                              __fmaf_rn(tau_r, cpv.y, R[a][1]));
                    const float tau_c = tcA[a];
                    const float col_c = ccA[a];
                    C[a][0] = __fmaf_rn(-cpv.x, tau_c,
                              __fmaf_rn(tpv.x, col_c, C[a][0]));
                    C[a][1] = __fmaf_rn(-cpv.y, tau_c,
                              __fmaf_rn(tpv.y, col_c, C[a][1]));
                }
            }
        }
        // ---- chain: readlane form (r18) + r24 reciprocal taus ----
        float TAU[4][2], CV[4][2];
#pragma unroll
        for (int j = 0; j < 4; ++j) {
            const int k = 8 * Pn + 2 * j;
            const float piv = RL(R[j][1], 4 * Pn + j);
            pf = __fmul_rn(pf, piv);          // step order
            const float rp = __fdiv_rn(1.0f, piv);   // ONE div per step
            TAU[j][0] = (g0 > k + 1) ? __fmul_rn(R[j][0], rp) : 0.0f;
            TAU[j][1] = (g1 > k + 1) ? __fmul_rn(R[j][1], rp) : 0.0f;
            CV[j][0]  = (g0 > k + 1) ? C[j][0] : 0.0f;
            CV[j][1]  = (g1 > k + 1) ? C[j][1] : 0.0f;
            *(float2*)&tauLDS[sv][j][pg] = make_float2(TAU[j][0], TAU[j][1]);
            *(float2*)&colLDS[sv][j][pg] = make_float2(CV[j][0], CV[j][1]);
#pragma unroll
            for (int j2 = j + 1; j2 < 4; ++j2) {
                const int ls = 4 * Pn + j2;
                const float tau_r = RL(TAU[j][0], ls);
                const float col_r = RL(CV[j][0], ls);
                R[j2][0] = __fmaf_rn(-col_r, TAU[j][0],
                           __fmaf_rn(tau_r, CV[j][0], R[j2][0]));
                R[j2][1] = __fmaf_rn(-col_r, TAU[j][1],
                           __fmaf_rn(tau_r, CV[j][1], R[j2][1]));
                const float tau_c = RL(TAU[j][1], ls);
                const float col_c = RL(CV[j][1], ls);
                C[j2][0] = __fmaf_rn(-CV[j][0], tau_c,
                           __fmaf_rn(TAU[j][0], col_c, C[j2][0]));
                C[j2][1] = __fmaf_rn(-CV[j][1], tau_c,
                           __fmaf_rn(TAU[j][1], col_c, C[j2][1]));
            }
        }
    };

    // ---- wave 0: panel-0/1 heads direct from F, then crew(0), overlapped
    //      with the bulk waves' A-gather (r21b). In-wave RAW, no barrier.
    if (wave == 0) {
        const int c0 = lane << 1;
        const int pc = POFF(c0);
#pragma unroll
        for (int st = 0; st < 2; ++st) {
#pragma unroll
            for (int j = 0; j < 4; ++j) {
                const int k = 8 * st + 2 * j;
                float2 rv, cv;
                rv.x = Fval(k, c0);
                rv.y = Fval(k, c0 + 1);
                cv.x = Fval(c0, k + 1);
                cv.y = Fval(c0 + 1, k + 1);
                *(float2*)&rS[st][j][pc] = rv;
                *(float2*)&cS[st][j][pc] = cv;
            }
        }
        crew2(0, false);
    }
    __syncthreads();

    // ---- 15 windows, ONE barrier each: bulk panel P || crew panel P+1 ----
    // wave w bulk-active for P < 2m. All 24 float4 LDS loads of the window
    // batched up-front (r22).
    for (int P = 0; P < 15; ++P) {
        if (wave >= 1 && P < 2 * m) {
            const int sp = P & 1;
            float4 TRv[4], CRv[4], T0v[4], T1v[4], C0v[4], C1v[4];
#pragma unroll
            for (int j = 0; j < 4; ++j) {
                TRv[j] = *(const float4*)&tauLDS[sp][j][prow];
                CRv[j] = *(const float4*)&colLDS[sp][j][prow];
                T0v[j] = *(const float4*)&tauLDS[sp][j][pcol];
                T1v[j] = *(const float4*)&tauLDS[sp][j][pcol + 4];
                C0v[j] = *(const float4*)&colLDS[sp][j][pcol];
                C1v[j] = *(const float4*)&colLDS[sp][j][pcol + 4];
            }
#pragma unroll
            for (int j = 0; j < 4; ++j) {
                const float tr[4] = {TRv[j].x, TRv[j].y, TRv[j].z, TRv[j].w};
                const float cr[4] = {CRv[j].x, CRv[j].y, CRv[j].z, CRv[j].w};
                const float tc[8] = {T0v[j].x, T0v[j].y, T0v[j].z, T0v[j].w,
                                     T1v[j].x, T1v[j].y, T1v[j].z, T1v[j].w};
                const float cc[8] = {C0v[j].x, C0v[j].y, C0v[j].z, C0v[j].w,
                                     C1v[j].x, C1v[j].y, C1v[j].z, C1v[j].w};
#pragma unroll
                for (int a = 0; a < 4; ++a) {
#pragma unroll
                    for (int c = 0; c < 8; ++c) {
                        A[a][c] = __fmaf_rn(-cr[a], tc[c],
                                  __fmaf_rn(tr[a], cc[c], A[a][c]));
                    }
                }
            }
            if (P <= 13) stage(P + 2, P & 1);   // updated through P
        }
        if (wave == 0) crew2(P + 1, true);      // panels 1..15
        __syncthreads();
    }

    if (t == 0) out[b] = pf;
}

extern "C" void kernel_launch(void* const* d_in, const int* in_sizes, int n_in,
                              void* d_out, int out_size, void* d_ws, size_t ws_size,
                              hipStream_t stream) {
    const float* x = (const float*)d_in[0];   // [128*128]
    const float* F = (const float*)d_in[1];   // [32640]
    float* out     = (float*)d_out;           // [128]
    (void)in_sizes; (void)n_in; (void)out_size; (void)d_ws; (void)ws_size;

    pfaffian_kernel<<<128, 512, 0, stream>>>(x, F, out);
}